// Round 3
// baseline (763.133 us; speedup 1.0000x reference)
//
#include <hip/hip_runtime.h>
#include <hip/hip_bf16.h>
#include <math.h>
#include <stdint.h>

#define B_SZ 256
#define H_SZ 1024
#define L_SZ 10
#define V_SZ 50257

typedef __attribute__((ext_vector_type(8))) short short8;
typedef __attribute__((ext_vector_type(4))) float floatx4;

// Pack 2 fp32 -> 2 bf16 in one dword: round-half-up (add 0x8000) + v_perm_b32.
// dst = [bf16(hi) : bf16(lo)]
__device__ __forceinline__ unsigned pack2(float lo, float hi) {
    unsigned a = __float_as_uint(hi) + 0x8000u;
    unsigned b = __float_as_uint(lo) + 0x8000u;
    return __builtin_amdgcn_perm(a, b, 0x07060302u);
}
__device__ __forceinline__ short8 pack8(float4 a, float4 b) {
    union { unsigned u[4]; short8 s; } r;
    r.u[0] = pack2(a.x, a.y); r.u[1] = pack2(a.z, a.w);
    r.u[2] = pack2(b.x, b.y); r.u[3] = pack2(b.z, b.w);
    return r.s;
}

// ---------------------------------------------------------------------------
// Big GEMM: C[256,N] = A[256,K] @ W[N,K]^T + bias.   (N=50257, K=1024)
// 256 thr = 4 waves; wave w owns cols n0 = bx*64 + w*16 (W read ONCE from HBM).
// Each wave computes all 256 rows (16 MFMA frags, 64 acc VGPRs).
// A chunk (256 rows x 32 k) staged cooperatively into LDS as bf16 each iter;
// A and W register-prefetched one chunk ahead. W fragments loaded direct from
// global in B-layout: lanes cover 16 rows x 128 B contiguous -> clean stream.
// MFMA layouts (verified r2): A/B frag [row=lane&15][k=(lane>>4)*8+j],
// C/D [row=(lane>>4)*4+i][col=lane&15].
// ---------------------------------------------------------------------------
#define ASTRIDE 40  // shorts per LDS row: 32 data + 8 pad (2-way banks on reads)

__global__ __launch_bounds__(256) void gemm_big(
    const float* __restrict__ A, const float* __restrict__ W,
    const float* __restrict__ bias, float* __restrict__ C, int N, int K)
{
    __shared__ __align__(16) short alds[256 * ASTRIDE];

    const int tid  = threadIdx.x;
    const int wave = tid >> 6, lane = tid & 63;
    const int quad = lane >> 4, l16 = lane & 15;

    const int n0 = blockIdx.x * 64 + wave * 16;
    int wrow = n0 + l16; if (wrow > N - 1) wrow = N - 1;   // clamp tail
    const float* wp = W + (size_t)wrow * K + quad * 8;
    const float* ap = A + (size_t)tid * K;                 // staging row = tid

    // prefetch chunk 0
    float4 wr0 = *(const float4*)(wp);
    float4 wr1 = *(const float4*)(wp + 4);
    float4 ar[8];
#pragma unroll
    for (int j = 0; j < 8; ++j) ar[j] = *(const float4*)(ap + 4 * j);

    floatx4 acc[16];
#pragma unroll
    for (int ms = 0; ms < 16; ++ms) acc[ms] = (floatx4){0.f, 0.f, 0.f, 0.f};

    short* arow = alds + tid * ASTRIDE;

    for (int k0 = 0; k0 < K; k0 += 32) {
        __syncthreads();  // WAR vs previous chunk's ds_reads
#pragma unroll
        for (int j = 0; j < 4; ++j) {
            union { unsigned u[4]; int4 v; } d;
            d.u[0] = pack2(ar[2*j].x,   ar[2*j].y);
            d.u[1] = pack2(ar[2*j].z,   ar[2*j].w);
            d.u[2] = pack2(ar[2*j+1].x, ar[2*j+1].y);
            d.u[3] = pack2(ar[2*j+1].z, ar[2*j+1].w);
            *(int4*)(arow + j * 8) = d.v;
        }
        __syncthreads();

        short8 bfrag = pack8(wr0, wr1);   // consume W regs for THIS chunk

        if (k0 + 32 < K) {                // prefetch next chunk (in flight
            wr0 = *(const float4*)(wp + k0 + 32);           // during compute)
            wr1 = *(const float4*)(wp + k0 + 36);
#pragma unroll
            for (int j = 0; j < 8; ++j)
                ar[j] = *(const float4*)(ap + k0 + 32 + 4 * j);
        }

#pragma unroll
        for (int ms = 0; ms < 16; ++ms) {
            short8 afrag = *(const short8*)(alds + (ms * 16 + l16) * ASTRIDE + quad * 8);
            acc[ms] = __builtin_amdgcn_mfma_f32_16x16x32_bf16(afrag, bfrag, acc[ms], 0, 0, 0);
        }
    }

    const int coln = n0 + l16;
    if (coln < N) {
        const float bv = bias[coln];
#pragma unroll
        for (int ms = 0; ms < 16; ++ms) {
            const int rbase = ms * 16 + quad * 4;
#pragma unroll
            for (int i = 0; i < 4; ++i)
                C[(size_t)(rbase + i) * N + coln] = acc[ms][i] + bv;
        }
    }
}

// ---------------------------------------------------------------------------
// Small GEMM, barrier-free: C[256,N] = A[256,K] @ W[N,K]^T + bias (opt relu).
// BN=16 per block (all 4 waves same cols, each wave a 64-row m-quarter).
// Everything loaded direct from global (L2-resident), perm-packed to bf16.
// Dual-operand: blockIdx.y==1 selects the second set (fuses gi+gh).
// N % 16 == 0, K % 32 == 0.
// ---------------------------------------------------------------------------
template<int RELU>
__global__ __launch_bounds__(256) void gemm_small(
    const float* __restrict__ A,  const float* __restrict__ W,
    const float* __restrict__ bias,  float* __restrict__ C,
    const float* __restrict__ A2, const float* __restrict__ W2,
    const float* __restrict__ bias2, float* __restrict__ C2,
    int N, int K)
{
    if (blockIdx.y == 1) { A = A2; W = W2; bias = bias2; C = C2; }

    const int tid  = threadIdx.x;
    const int wave = tid >> 6, lane = tid & 63;
    const int quad = lane >> 4, l16 = lane & 15;

    const int n0 = blockIdx.x * 16;
    const int m0 = wave * 64;

    const float* wp  = W + (size_t)(n0 + l16) * K + quad * 8;
    const float* ap0 = A + (size_t)(m0 + l16) * K + quad * 8;

    floatx4 acc[4];
#pragma unroll
    for (int ms = 0; ms < 4; ++ms) acc[ms] = (floatx4){0.f, 0.f, 0.f, 0.f};

#pragma unroll 2
    for (int k0 = 0; k0 < K; k0 += 32) {
        float4 w0 = *(const float4*)(wp + k0);
        float4 w1 = *(const float4*)(wp + k0 + 4);
        short8 bfrag = pack8(w0, w1);
#pragma unroll
        for (int ms = 0; ms < 4; ++ms) {
            const float* a = ap0 + (size_t)(ms * 16) * K + k0;
            float4 a0 = *(const float4*)(a);
            float4 a1 = *(const float4*)(a + 4);
            short8 afrag = pack8(a0, a1);
            acc[ms] = __builtin_amdgcn_mfma_f32_16x16x32_bf16(afrag, bfrag, acc[ms], 0, 0, 0);
        }
    }

    const int coln = n0 + l16;
    const float bv = bias[coln];
#pragma unroll
    for (int ms = 0; ms < 4; ++ms) {
        const int rbase = m0 + ms * 16 + quad * 4;
#pragma unroll
        for (int i = 0; i < 4; ++i) {
            float v = acc[ms][i] + bv;
            if (RELU) v = fmaxf(v, 0.f);
            C[(size_t)(rbase + i) * N + coln] = v;
        }
    }
}

// ---------------------------------------------------------------------------
// Embedding gather + attention logits + softmax + context vector.
// ---------------------------------------------------------------------------
__global__ __launch_bounds__(256) void attn_kernel(
    const int* __restrict__ tokens, const float* __restrict__ hidden,
    const float* __restrict__ enc, const float* __restrict__ emb,
    const float* __restrict__ attn_W, const float* __restrict__ attn_b,
    float* __restrict__ cat_out, float* __restrict__ attn_w_out)
{
    const int b = blockIdx.x;
    const int tid = threadIdx.x;
    const int tok = tokens[b];
    const float* erow = emb + (size_t)tok * H_SZ;
    const float* hrow = hidden + (size_t)b * H_SZ;

    __shared__ float red[L_SZ][256];
    __shared__ float wts[L_SZ];

    float acc[L_SZ];
#pragma unroll
    for (int l = 0; l < L_SZ; ++l) acc[l] = 0.f;

    for (int i = tid; i < H_SZ; i += 256) {
        float e = erow[i];
        float hv = hrow[i];
        cat_out[(size_t)b * 2 * H_SZ + i] = e;
#pragma unroll
        for (int l = 0; l < L_SZ; ++l) {
            acc[l] += e * attn_W[l * 2 * H_SZ + i] + hv * attn_W[l * 2 * H_SZ + H_SZ + i];
        }
    }
#pragma unroll
    for (int l = 0; l < L_SZ; ++l) red[l][tid] = acc[l];
    __syncthreads();
    for (int s = 128; s > 0; s >>= 1) {
        if (tid < s) {
#pragma unroll
            for (int l = 0; l < L_SZ; ++l) red[l][tid] += red[l][tid + s];
        }
        __syncthreads();
    }
    if (tid == 0) {
        float m = -INFINITY;
        float lg[L_SZ];
#pragma unroll
        for (int l = 0; l < L_SZ; ++l) {
            lg[l] = red[l][0] + attn_b[l];
            m = fmaxf(m, lg[l]);
        }
        float s = 0.f;
#pragma unroll
        for (int l = 0; l < L_SZ; ++l) {
            float e = expf(lg[l] - m);
            wts[l] = e;
            s += e;
        }
        float inv = 1.f / s;
#pragma unroll
        for (int l = 0; l < L_SZ; ++l) {
            wts[l] *= inv;
            attn_w_out[(size_t)b * L_SZ + l] = wts[l];
        }
    }
    __syncthreads();

    for (int i = tid; i < H_SZ; i += 256) {
        float s = 0.f;
#pragma unroll
        for (int l = 0; l < L_SZ; ++l) s += wts[l] * enc[l * H_SZ + i];
        cat_out[(size_t)b * 2 * H_SZ + H_SZ + i] = s;
    }
}

// ---------------------------------------------------------------------------
// GRU pointwise combine
// ---------------------------------------------------------------------------
__global__ __launch_bounds__(256) void gru_combine(
    const float* __restrict__ gi, const float* __restrict__ gh,
    const float* __restrict__ hidden, float* __restrict__ h_new)
{
    int idx = blockIdx.x * blockDim.x + threadIdx.x;
    if (idx >= B_SZ * H_SZ) return;
    int b = idx >> 10;
    int j = idx & (H_SZ - 1);
    const float* gib = gi + (size_t)b * 3 * H_SZ;
    const float* ghb = gh + (size_t)b * 3 * H_SZ;
    float i_r = gib[j], i_z = gib[H_SZ + j], i_n = gib[2 * H_SZ + j];
    float h_r = ghb[j], h_z = ghb[H_SZ + j], h_n = ghb[2 * H_SZ + j];
    float r = 1.f / (1.f + expf(-(i_r + h_r)));
    float z = 1.f / (1.f + expf(-(i_z + h_z)));
    float n = tanhf(i_n + r * h_n);
    float h = hidden[idx];
    h_new[idx] = (1.f - z) * n + z * h;
}

// ---------------------------------------------------------------------------
// log-softmax, 2 passes, float4, online max+sum. One block (1024 thr) per row.
// ---------------------------------------------------------------------------
__global__ __launch_bounds__(1024) void logsoftmax_v2(float* __restrict__ out)
{
    const int b = blockIdx.x;
    float* row = out + (size_t)b * V_SZ;
    const int tid = threadIdx.x;
    const int wave = tid >> 6;
    const int lane = tid & 63;

    const int head = (int)(((16u - ((uintptr_t)row & 15u)) & 15u) >> 2);  // 0..3
    const int nv = (V_SZ - head) >> 2;
    const float4* r4 = (const float4*)(row + head);
    const int tail_start = head + (nv << 2);

    float m = -INFINITY, s = 0.f;
    if (tid < head) { float v = row[tid]; m = v; s = 1.f; }
    for (int i = tid; i < nv; i += 1024) {
        float4 v = r4[i];
        float mv = fmaxf(fmaxf(v.x, v.y), fmaxf(v.z, v.w));
        if (mv > m) { s *= expf(m - mv); m = mv; }
        s += expf(v.x - m) + expf(v.y - m) + expf(v.z - m) + expf(v.w - m);
    }
    for (int i = tail_start + tid; i < V_SZ; i += 1024) {
        float v = row[i];
        if (v > m) { s *= expf(m - v); m = v; }
        s += expf(v - m);
    }

    for (int off = 32; off > 0; off >>= 1) {
        float m2 = __shfl_down(m, off);
        float s2 = __shfl_down(s, off);
        float mn = fmaxf(m, m2);
        s = s * expf(m - mn) + s2 * expf(m2 - mn);
        m = mn;
    }
    __shared__ float smax[16], ssum[16], slse;
    if (lane == 0) { smax[wave] = m; ssum[wave] = s; }
    __syncthreads();
    if (tid == 0) {
        float M = smax[0], S = ssum[0];
        for (int w = 1; w < 16; ++w) {
            float mn = fmaxf(M, smax[w]);
            S = S * expf(M - mn) + ssum[w] * expf(smax[w] - mn);
            M = mn;
        }
        slse = M + logf(S);
    }
    __syncthreads();
    const float lse = slse;

    if (tid < head) row[tid] -= lse;
    float4* w4 = (float4*)(row + head);
    for (int i = tid; i < nv; i += 1024) {
        float4 v = r4[i];
        v.x -= lse; v.y -= lse; v.z -= lse; v.w -= lse;
        w4[i] = v;
    }
    for (int i = tail_start + tid; i < V_SZ; i += 1024) row[i] -= lse;
}

// ---------------------------------------------------------------------------
extern "C" void kernel_launch(void* const* d_in, const int* in_sizes, int n_in,
                              void* d_out, int out_size, void* d_ws, size_t ws_size,
                              hipStream_t stream)
{
    const int*   tokens = (const int*)d_in[0];
    const float* hidden = (const float*)d_in[1];
    const float* enc    = (const float*)d_in[2];
    const float* emb    = (const float*)d_in[3];
    const float* attn_W = (const float*)d_in[4];
    const float* attn_b = (const float*)d_in[5];
    const float* comb_W = (const float*)d_in[6];
    const float* comb_b = (const float*)d_in[7];
    const float* W_ih   = (const float*)d_in[8];
    const float* W_hh   = (const float*)d_in[9];
    const float* b_ih   = (const float*)d_in[10];
    const float* b_hh   = (const float*)d_in[11];
    const float* out_W  = (const float*)d_in[12];
    const float* out_b  = (const float*)d_in[13];

    float* out = (float*)d_out;
    float* logits     = out;                                   // [B,V]
    float* h_new      = out + (size_t)B_SZ * V_SZ;             // [B,H]
    float* attn_w_out = h_new + (size_t)B_SZ * H_SZ;           // [B,L]

    // Scratch in out-region-0 (dead before the big GEMM overwrites it)
    float* cat = logits;                          // [B, 2H]
    float* x   = cat + (size_t)B_SZ * 2 * H_SZ;   // [B, H]
    float* gi  = x   + (size_t)B_SZ * H_SZ;       // [B, 3H]
    float* gh  = gi  + (size_t)B_SZ * 3 * H_SZ;   // [B, 3H]

    attn_kernel<<<B_SZ, 256, 0, stream>>>(tokens, hidden, enc, emb, attn_W, attn_b,
                                          cat, attn_w_out);
    // x = relu(cat @ comb_W^T + comb_b)          [256 x 1024, K=2048]
    gemm_small<1><<<dim3(H_SZ / 16, 1), 256, 0, stream>>>(
        cat, comb_W, comb_b, x,  cat, comb_W, comb_b, x,  H_SZ, 2 * H_SZ);
    // gi = x @ W_ih^T + b_ih ; gh = h @ W_hh^T + b_hh   (fused, grid.y=2)
    gemm_small<0><<<dim3(3 * H_SZ / 16, 2), 256, 0, stream>>>(
        x, W_ih, b_ih, gi,  hidden, W_hh, b_hh, gh,  3 * H_SZ, H_SZ);
    gru_combine<<<(B_SZ * H_SZ + 255) / 256, 256, 0, stream>>>(gi, gh, hidden, h_new);
    // logits = h_new @ out_W^T + out_b           [256 x 50257, K=1024]
    gemm_big<<<dim3((V_SZ + 63) / 64, 1), 256, 0, stream>>>(
        h_new, out_W, out_b, logits, V_SZ, H_SZ);
    logsoftmax_v2<<<B_SZ, 1024, 0, stream>>>(logits);
}